// Round 19
// baseline (261.737 us; speedup 1.0000x reference)
//
#include <hip/hip_runtime.h>
#include <hip/hip_bf16.h>
#include <cstdint>

// MLA: B=2, T=2048, H=16, d_nope=128, d_rope=64, d_qk=192, d_v=128,
// kv_lora=512, q_lora=1536, hidden=2048. Output f32 [4096][2048].

typedef __bf16 bf16;
typedef __bf16 bf16x8 __attribute__((ext_vector_type(8)));
typedef __bf16 bf16x4v __attribute__((ext_vector_type(4)));
typedef float f32x4 __attribute__((ext_vector_type(4)));

#define TSEQ 2048
#define MR 4096  // B*T

typedef const uint32_t __attribute__((address_space(1))) * gas1_t;
typedef uint32_t __attribute__((address_space(3))) * las3_t;

static __device__ __forceinline__ void gload_lds16(const void* g, void* l) {
  __builtin_amdgcn_global_load_lds(
      reinterpret_cast<gas1_t>(reinterpret_cast<uintptr_t>(g)),
      reinterpret_cast<las3_t>(reinterpret_cast<uintptr_t>(l)), 16, 0, 0);
}

static __device__ __forceinline__ f32x4 mfma16(bf16x8 a, bf16x8 b, f32x4 c) {
  return __builtin_amdgcn_mfma_f32_16x16x32_bf16(a, b, c, 0, 0, 0);
}

// ---------------- fused prep kernel (proven round 11) ----------------------
static __device__ __forceinline__ void do_transpose(
    const float* __restrict__ W, bf16* __restrict__ Wt, int K, int N, int bi,
    int bj, float (*t)[33]) {
  int c = threadIdx.x & 31, r0 = threadIdx.x >> 5;
#pragma unroll
  for (int rr = 0; rr < 32; rr += 8)
    t[rr + r0][c] = W[(size_t)(bj * 32 + rr + r0) * N + bi * 32 + c];
  __syncthreads();
#pragma unroll
  for (int rr = 0; rr < 32; rr += 8)
    Wt[(size_t)(bi * 32 + rr + r0) * K + bj * 32 + c] = (bf16)t[c][rr + r0];
}

#define PREP_BLOCKS (8192 + 3072 + 1152 + 4608 + 2048 + 4096 + 192 + 256)

__global__ __launch_bounds__(256) void k_prep(
    const float* __restrict__ x, const float* __restrict__ q_a_w,
    const float* __restrict__ kv_a_w, const float* __restrict__ q_b_w,
    const float* __restrict__ kv_b_w, const float* __restrict__ o_w,
    bf16* __restrict__ x_bf, bf16* __restrict__ ab_wt,
    bf16* __restrict__ qb_wt, bf16* __restrict__ kvb_wt,
    bf16* __restrict__ o_wt, float* __restrict__ rt) {
  __shared__ float t[32][33];
  int nb = blockIdx.x;
  const int tid = threadIdx.x;
  if (nb < 8192) {  // cvt x -> bf16
    int i = nb * 256 + tid;
    float4 f = reinterpret_cast<const float4*>(x)[i];
    bf16x4v o = {(bf16)f.x, (bf16)f.y, (bf16)f.z, (bf16)f.w};
    reinterpret_cast<bf16x4v*>(x_bf)[i] = o;
    return;
  }
  nb -= 8192;
  if (nb < 3072) { do_transpose(q_a_w, ab_wt, 2048, 1536, nb % 48, nb / 48, t); return; }
  nb -= 3072;
  if (nb < 1152) {
    do_transpose(kv_a_w, ab_wt + (size_t)1536 * 2048, 2048, 576, nb % 18, nb / 18, t);
    return;
  }
  nb -= 1152;
  if (nb < 4608) { do_transpose(q_b_w, qb_wt, 1536, 3072, nb % 96, nb / 96, t); return; }
  nb -= 4608;
  if (nb < 2048) { do_transpose(kv_b_w, kvb_wt, 512, 4096, nb % 128, nb / 128, t); return; }
  nb -= 2048;
  if (nb < 4096) { do_transpose(o_w, o_wt, 2048, 2048, nb % 64, nb / 64, t); return; }
  nb -= 4096;
  if (nb < 192) {  // zero-fill pad rows 2112..2303 of ab_wt
    uint4 z = make_uint4(0, 0, 0, 0);
    reinterpret_cast<uint4*>(ab_wt + (size_t)2112 * 2048)[nb * 256 + tid] = z;
    return;
  }
  nb -= 192;
  {  // rope table: rt[t][2j]={cos}, [2j+1]={sin}
    int idx = nb * 256 + tid;
    int tt = idx >> 5, j = idx & 31;
    float freq = exp2f(-(float)j * (1.0f / 32.0f) * log2f(500000.0f));
    float ang = (float)tt * freq;
    rt[tt * 64 + 2 * j] = cosf(ang);
    rt[tt * 64 + 2 * j + 1] = sinf(ang);
  }
}

// ---------------- fused norms: q-rmsnorm + kv-rmsnorm + k-rope -------------
__global__ __launch_bounds__(64) void k_norms(
    const bf16* __restrict__ qac, const float* __restrict__ qw,
    const float* __restrict__ kvw, const float* __restrict__ rt,
    bf16* __restrict__ q_a_n, bf16* __restrict__ kv_c_n,
    bf16* __restrict__ kr) {
  int row = blockIdx.x, lane = threadIdx.x;
  const bf16* ip = qac + (size_t)row * 2304;
  bf16x8 v[3];
  float ss = 0.f;
#pragma unroll
  for (int c = 0; c < 3; ++c) {
    v[c] = *reinterpret_cast<const bf16x8*>(ip + c * 512 + lane * 8);
#pragma unroll
    for (int e = 0; e < 8; ++e) { float f = (float)v[c][e]; ss += f * f; }
  }
#pragma unroll
  for (int m = 1; m <= 32; m <<= 1) ss += __shfl_xor(ss, m);
  float rs = rsqrtf(ss / 1536.0f + 1e-6f);
  bf16* op = q_a_n + (size_t)row * 1536;
#pragma unroll
  for (int c = 0; c < 3; ++c) {
    bf16x8 o;
#pragma unroll
    for (int e = 0; e < 8; ++e)
      o[e] = (bf16)((float)v[c][e] * rs * qw[c * 512 + lane * 8 + e]);
    *reinterpret_cast<bf16x8*>(op + c * 512 + lane * 8) = o;
  }
  bf16x8 kvv = *reinterpret_cast<const bf16x8*>(ip + 1536 + lane * 8);
  float s2 = 0.f;
#pragma unroll
  for (int e = 0; e < 8; ++e) { float f = (float)kvv[e]; s2 += f * f; }
#pragma unroll
  for (int m = 1; m <= 32; m <<= 1) s2 += __shfl_xor(s2, m);
  float rs2 = rsqrtf(s2 / 512.0f + 1e-6f);
  bf16x8 o2;
#pragma unroll
  for (int e = 0; e < 8; ++e)
    o2[e] = (bf16)((float)kvv[e] * rs2 * kvw[lane * 8 + e]);
  *reinterpret_cast<bf16x8*>(kv_c_n + (size_t)row * 512 + lane * 8) = o2;
  if (lane < 32) {
    int t = row & (TSEQ - 1);
    float x0 = (float)ip[2048 + 2 * lane], x1 = (float)ip[2048 + 2 * lane + 1];
    float c = rt[t * 64 + 2 * lane], s = rt[t * 64 + 2 * lane + 1];
    kr[(size_t)row * 64 + lane] = (bf16)(x0 * c - x1 * s);
    kr[(size_t)row * 64 + 32 + lane] = (bf16)(x1 * c + x0 * s);
  }
}

// ---------- 4-phase 256x128 GEMM body (proven on o-proj, round 17) ---------
#define GPN(BUF, KH, STAGE_STMT, WAIT_STMT)                                   \
  {                                                                           \
    bf16x8 bfr[4];                                                            \
    _Pragma("unroll") for (int ni = 0; ni < 4; ++ni) {                        \
      int row = wn * 64 + ni * 16 + lr;                                       \
      bfr[ni] = *reinterpret_cast<const bf16x8*>(                             \
          &Bs[BUF][row * 64 + ((((KH)*4 + lg) ^ (row & 7)) * 8)]);            \
    }                                                                         \
    bf16x8 af[4];                                                             \
    _Pragma("unroll") for (int mi = 0; mi < 4; ++mi) {                        \
      int row = wm * 64 + mi * 16 + lr;                                       \
      af[mi] = *reinterpret_cast<const bf16x8*>(                              \
          &As[BUF][row * 64 + ((((KH)*4 + lg) ^ (row & 7)) * 8)]);            \
    }                                                                         \
    STAGE_STMT;                                                               \
    __builtin_amdgcn_s_barrier();                                             \
    __builtin_amdgcn_s_setprio(1);                                            \
    _Pragma("unroll") for (int mi = 0; mi < 4; ++mi)                          \
        _Pragma("unroll") for (int ni = 0; ni < 4; ++ni)                      \
            acc[mi][ni] = mfma16(af[mi], bfr[ni], acc[mi][ni]);               \
    __builtin_amdgcn_s_setprio(0);                                            \
    WAIT_STMT;                                                                \
    __builtin_amdgcn_s_barrier();                                             \
  }

template <bool OUT_F32>
static __device__ __forceinline__ void gemm4n_body(
    const bf16* __restrict__ A, const bf16* __restrict__ Bt,
    void* __restrict__ C, int N, int K, int bi, int bj, bf16 (*As)[16384],
    bf16 (*Bs)[8192]) {
  const int tid = threadIdx.x, lane = tid & 63, w = tid >> 6;
  const int lg = lane >> 4, lr = lane & 15;
  const int wm = w >> 1, wn = w & 1;
  const int m0 = bj * 256, n0 = bi * 128;
  const int T = K >> 7;

  f32x4 acc[4][4] = {};

  auto stA = [&](int tau, int h) {
    char* dst = (char*)&As[tau & 1][0] + h * 16384;
#pragma unroll
    for (int j = 0; j < 2; ++j) {
      int c = j * 512 + tid;
      int row = c >> 3, slot = c & 7;
      gload_lds16(A + (size_t)(m0 + h * 128 + row) * K + tau * 64 +
                      ((slot ^ (row & 7)) * 8),
                  dst + (size_t)(j * 512 + w * 64) * 16);
    }
  };
  auto stB = [&](int tau) {
    char* dst = (char*)&Bs[tau & 1][0];
#pragma unroll
    for (int j = 0; j < 2; ++j) {
      int c = j * 512 + tid;
      int row = c >> 3, slot = c & 7;
      gload_lds16(Bt + (size_t)(n0 + row) * K + tau * 64 +
                      ((slot ^ (row & 7)) * 8),
                  dst + (size_t)(j * 512 + w * 64) * 16);
    }
  };

  stA(0, 0); stA(0, 1); stB(0); stA(1, 0);
  asm volatile("s_waitcnt vmcnt(2)" ::: "memory");
  __builtin_amdgcn_s_barrier();

  for (int t = 0; t < T - 1; ++t) {
    const int u1 = 2 * t + 1, s2 = 2 * t + 2, s3 = 2 * t + 3;
    GPN(0, 0, stA(u1, 1), ((void)0));
    GPN(0, 1, { stB(u1); stA(s2, 0); },
        asm volatile("s_waitcnt vmcnt(2)" ::: "memory"));
    GPN(1, 0, stA(s2, 1), ((void)0));
    GPN(1, 1, { stB(s2); stA(s3, 0); },
        asm volatile("s_waitcnt vmcnt(2)" ::: "memory"));
  }
  {
    const int u1 = 2 * T - 1;
    GPN(0, 0, stA(u1, 1), ((void)0));
    GPN(0, 1, stB(u1),
        asm volatile("s_waitcnt vmcnt(0)" ::: "memory"));
    GPN(1, 0, ((void)0), ((void)0));
    GPN(1, 1, ((void)0), ((void)0));
  }

#pragma unroll
  for (int mi = 0; mi < 4; ++mi)
#pragma unroll
    for (int ni = 0; ni < 4; ++ni) {
      int col = n0 + wn * 64 + ni * 16 + lr;
#pragma unroll
      for (int r = 0; r < 4; ++r) {
        int rowg = m0 + wm * 64 + mi * 16 + lg * 4 + r;
        if (OUT_F32)
          reinterpret_cast<float*>(C)[(size_t)rowg * N + col] = acc[mi][ni][r];
        else
          reinterpret_cast<bf16*>(C)[(size_t)rowg * N + col] =
              (bf16)acc[mi][ni][r];
      }
    }
}

template <bool OUT_F32>
__global__ __launch_bounds__(512, 2) void k_gemm4n(const bf16* __restrict__ A,
                                                   const bf16* __restrict__ Bt,
                                                   void* __restrict__ C, int N,
                                                   int K) {
  __shared__ bf16 As[2][16384];
  __shared__ bf16 Bs[2][8192];
  const int nwg = gridDim.x * gridDim.y;
  const int orig = blockIdx.y * gridDim.x + blockIdx.x;
  const int wgid = (orig & 7) * (nwg >> 3) + (orig >> 3);
  gemm4n_body<OUT_F32>(A, Bt, C, N, K, wgid % gridDim.x, wgid / gridDim.x, As,
                       Bs);
}

// q_b (384 blocks, T=12, first) co-dispatched with kv_b (512 blocks, T=4):
// finer 256x128 granularity -> greedy fill lands every CU near the ideal
// (4608+2048)/256 = 26 k-tile units (old 256^2 dual: worst CU = 32).
__global__ __launch_bounds__(512, 2) void k_gemm4n_dual(
    const bf16* __restrict__ A1, const bf16* __restrict__ B1,
    bf16* __restrict__ C1, const bf16* __restrict__ A2,
    const bf16* __restrict__ B2, bf16* __restrict__ C2) {
  __shared__ bf16 As[2][16384];
  __shared__ bf16 Bs[2][8192];
  int id = blockIdx.x;
  if (id < 384) {
    int wg = (id & 7) * 48 + (id >> 3);  // T1 within sub-grid (384 % 8 == 0)
    gemm4n_body<false>(A1, B1, C1, 3072, 1536, wg % 24, wg / 24, As, Bs);
  } else {
    int s = id - 384;
    int wg = (s & 7) * 64 + (s >> 3);  // 512 % 8 == 0
    gemm4n_body<false>(A2, B2, C2, 4096, 512, wg % 32, wg / 32, As, Bs);
  }
}

// ---------- 4-phase 128x128 GEMM, 64K LDS -> 2 blocks/CU (qac) -------------
#define GPS(BUF, KH, STAGE_STMT, WAIT_STMT)                                   \
  {                                                                           \
    bf16x8 bfr[4];                                                            \
    _Pragma("unroll") for (int ni = 0; ni < 4; ++ni) {                        \
      int row = wc * 64 + ni * 16 + lr;                                       \
      bfr[ni] = *reinterpret_cast<const bf16x8*>(                             \
          &Bs[BUF][row * 64 + ((((KH)*4 + lg) ^ (row & 7)) * 8)]);            \
    }                                                                         \
    bf16x8 af[2];                                                             \
    _Pragma("unroll") for (int mi = 0; mi < 2; ++mi) {                        \
      int row = wr * 32 + mi * 16 + lr;                                       \
      af[mi] = *reinterpret_cast<const bf16x8*>(                              \
          &As[BUF][row * 64 + ((((KH)*4 + lg) ^ (row & 7)) * 8)]);            \
    }                                                                         \
    STAGE_STMT;                                                               \
    __builtin_amdgcn_s_barrier();                                             \
    __builtin_amdgcn_s_setprio(1);                                            \
    _Pragma("unroll") for (int mi = 0; mi < 2; ++mi)                          \
        _Pragma("unroll") for (int ni = 0; ni < 4; ++ni)                      \
            acc[mi][ni] = mfma16(af[mi], bfr[ni], acc[mi][ni]);               \
    __builtin_amdgcn_s_setprio(0);                                            \
    WAIT_STMT;                                                                \
    __builtin_amdgcn_s_barrier();                                             \
  }

template <bool OUT_F32>
__global__ __launch_bounds__(512, 2) void k_gemm2s(const bf16* __restrict__ A,
                                                   const bf16* __restrict__ Bt,
                                                   void* __restrict__ C, int N,
                                                   int K) {
  __shared__ bf16 As[2][8192];  // 128 rows x 64 k
  __shared__ bf16 Bs[2][8192];  // 128 rows x 64 k
  const int tid = threadIdx.x, lane = tid & 63, w = tid >> 6;
  const int lg = lane >> 4, lr = lane & 15;
  const int wr = w >> 1, wc = w & 1;
  const int nwg = gridDim.x * gridDim.y;
  const int orig = blockIdx.y * gridDim.x + blockIdx.x;
  const int wgid = (orig & 7) * (nwg >> 3) + (orig >> 3);
  const int m0 = (wgid / gridDim.x) * 128, n0 = (wgid % gridDim.x) * 128;
  const int T = K >> 7;

  f32x4 acc[2][4] = {};

  auto stA = [&](int tau) {
    char* dst = (char*)&As[tau & 1][0];
#pragma unroll
    for (int j = 0; j < 2; ++j) {
      int c = j * 512 + tid;
      int row = c >> 3, slot = c & 7;
      gload_lds16(A + (size_t)(m0 + row) * K + tau * 64 +
                      ((slot ^ (row & 7)) * 8),
                  dst + (size_t)(j * 512 + w * 64) * 16);
    }
  };
  auto stB = [&](int tau) {
    char* dst = (char*)&Bs[tau & 1][0];
#pragma unroll
    for (int j = 0; j < 2; ++j) {
      int c = j * 512 + tid;
      int row = c >> 3, slot = c & 7;
      gload_lds16(Bt + (size_t)(n0 + row) * K + tau * 64 +
                      ((slot ^ (row & 7)) * 8),
                  dst + (size_t)(j * 512 + w * 64) * 16);
    }
  };

  stA(0); stB(0); stA(1);
  asm volatile("s_waitcnt vmcnt(2)" ::: "memory");
  __builtin_amdgcn_s_barrier();

  for (int t = 0; t < T - 1; ++t) {
    const int u1 = 2 * t + 1, s2 = 2 * t + 2, s3 = 2 * t + 3;
    GPS(0, 0, stB(u1), ((void)0));
    GPS(0, 1, stA(s2),
        asm volatile("s_waitcnt vmcnt(2)" ::: "memory"));
    GPS(1, 0, stB(s2), ((void)0));
    GPS(1, 1, stA(s3),
        asm volatile("s_waitcnt vmcnt(2)" ::: "memory"));
  }
  {
    const int u1 = 2 * T - 1;
    GPS(0, 0, stB(u1), ((void)0));
    GPS(0, 1, ((void)0),
        asm volatile("s_waitcnt vmcnt(0)" ::: "memory"));
    GPS(1, 0, ((void)0), ((void)0));
    GPS(1, 1, ((void)0), ((void)0));
  }

#pragma unroll
  for (int mi = 0; mi < 2; ++mi)
#pragma unroll
    for (int ni = 0; ni < 4; ++ni) {
      int col = n0 + wc * 64 + ni * 16 + lr;
#pragma unroll
      for (int r = 0; r < 4; ++r) {
        int rowg = m0 + wr * 32 + mi * 16 + lg * 4 + r;
        if (OUT_F32)
          reinterpret_cast<float*>(C)[(size_t)rowg * N + col] = acc[mi][ni][r];
        else
          reinterpret_cast<bf16*>(C)[(size_t)rowg * N + col] =
              (bf16)acc[mi][ni][r];
      }
    }
}

// ---------------- causal flash attention v6r (round-16, known-good) --------
__global__ __launch_bounds__(512, 2) void k_attn(const bf16* __restrict__ q,
                                                 const bf16* __restrict__ kv,
                                                 const bf16* __restrict__ kr,
                                                 const float* __restrict__ rt,
                                                 bf16* __restrict__ o) {
  __shared__ bf16 Kn[2][64 * 128];  // linear chunks; data col = j^(row&15)
  __shared__ bf16 Kr[2][64 * 64];   // data col = j^(row&7)
  __shared__ bf16 Vs[2][64 * 128];  // fragment-packed V^T
  __shared__ bf16 Ps[8 * 1024];     // per-wave P [16 q][64 k] swizzled
  const int tid = threadIdx.x, lane = tid & 63, w = tid >> 6;
  const int lg = lane >> 4, lr = lane & 15;
  const float qsc = 0.07216878364870323f * 1.44269504088896f;  // 192^-.5*log2e
  uint4 vreg[2];
  const int vrr = tid & 31, vvc = tid >> 5;

  for (int t = 0; t < 2; ++t) {
    const int id = t ? 511 - (int)blockIdx.x : (int)blockIdx.x;
    const int qt = 15 - (id >> 5);
    const int bh = id & 31;
    const int b = bh >> 4, h = bh & 15;
    const int q0 = qt * 128;
    const size_t rowbase = (size_t)b * TSEQ;
    const int nkt = 2 * qt + 2;
    const int qg = q0 + w * 16 + lr;

    auto issue_loads = [&](int kbase, int buf) {
#pragma unroll
      for (int kk = 0; kk < 2; ++kk)
        vreg[kk] = *reinterpret_cast<const uint4*>(
            kv + (rowbase + kbase + vrr * 2 + kk) * 4096 + h * 256 + 128 +
            vvc * 8);
#pragma unroll
      for (int i = 0; i < 2; ++i) {
        int c = i * 512 + tid;
        int row = c >> 4, j = c & 15;
        gload_lds16(
            kv + (rowbase + kbase + row) * 4096 + h * 256 +
                ((j ^ (row & 15)) * 8),
            (char*)&Kn[buf][0] + (size_t)(i * 512 + w * 64) * 16);
      }
      {
        int row = tid >> 3, j = tid & 7;
        gload_lds16(kr + (rowbase + kbase + row) * 64 + ((j ^ (row & 7)) * 8),
                    (char*)&Kr[buf][0] + (size_t)(w * 64) * 16);
      }
    };

    auto write_vs = [&](int buf) {
      const int kb0 = vrr * 2;
      const int cC = kb0 >> 5, g = (kb0 >> 3) & 3, j0 = kb0 & 7;
      const uint32_t* r0 = reinterpret_cast<const uint32_t*>(&vreg[0]);
      const uint32_t* r1 = reinterpret_cast<const uint32_t*>(&vreg[1]);
#pragma unroll
      for (int e = 0; e < 8; ++e) {
        uint32_t h0 = (r0[e >> 1] >> ((e & 1) * 16)) & 0xffffu;
        uint32_t h1 = (r1[e >> 1] >> ((e & 1) * 16)) & 0xffffu;
        int vd = vvc * 8 + e;
        int slot = (vd & 15) ^ g;
        *reinterpret_cast<uint32_t*>(
            &Vs[buf][((cC * 8 + (vd >> 4)) * 4 + g) * 128 + slot * 8 + j0]) =
            h0 | (h1 << 16);
      }
    };

    // Q fragments: nope cols direct; rope cols computed in-register from rt.
    bf16x8 qf[6];
    {
      const bf16* qp = q + (rowbase + qg) * 3072 + h * 192;
#pragma unroll
      for (int dc = 0; dc < 4; ++dc) {
        bf16x8 v = *reinterpret_cast<const bf16x8*>(qp + dc * 32 + lg * 8);
#pragma unroll
        for (int e = 0; e < 8; ++e) v[e] = (bf16)((float)v[e] * qsc);
        qf[dc] = v;
      }
      bf16x8 ra = *reinterpret_cast<const bf16x8*>(qp + 128 + lg * 16);
      bf16x8 rb = *reinterpret_cast<const bf16x8*>(qp + 128 + lg * 16 + 8);
      const float* rtp = rt + (size_t)qg * 64 + lg * 16;
      float4 r0 = *reinterpret_cast<const float4*>(rtp);
      float4 r1 = *reinterpret_cast<const float4*>(rtp + 4);
      float4 r2 = *reinterpret_cast<const float4*>(rtp + 8);
      float4 r3 = *reinterpret_cast<const float4*>(rtp + 12);
      float rc[8] = {r0.x, r0.z, r1.x, r1.z, r2.x, r2.z, r3.x, r3.z};
      float rs_[8] = {r0.y, r0.w, r1.y, r1.w, r2.y, r2.w, r3.y, r3.w};
      bf16x8 v4, v5;
#pragma unroll
      for (int j = 0; j < 8; ++j) {
        float x0 = (float)((j < 4) ? ra[2 * j] : rb[2 * j - 8]);
        float x1 = (float)((j < 4) ? ra[2 * j + 1] : rb[2 * j - 7]);
        v4[j] = (bf16)((x0 * rc[j] - x1 * rs_[j]) * qsc);
        v5[j] = (bf16)((x1 * rc[j] + x0 * rs_[j]) * qsc);
      }
      qf[4] = v4;
      qf[5] = v5;
    }

    f32x4 oacc[8] = {};
    float m_run = -1e30f, l_run = 0.f;

    issue_loads(0, 0);
    write_vs(0);
    __syncthreads();

    for (int kt = 0; kt < nkt; ++kt) {
      const int kbase = kt * 64;
      const int buf = kt & 1;
      const bool more = (kt + 1 < nkt);
      if (more) issue_loads(kbase + 64, buf ^ 1);

      if (kbase <= q0 + w * 16 + 15) {
        f32x4 sacc[4];
#pragma unroll
        for (int kb = 0; kb < 4; ++kb) {
          const int row = kb * 16 + lr;
          bf16x8 kf[6];
#pragma unroll
          for (int dc = 0; dc < 4; ++dc)
            kf[dc] = *reinterpret_cast<const bf16x8*>(
                &Kn[buf][row * 128 + (((dc * 4 + lg) ^ (row & 15)) * 8)]);
#pragma unroll
          for (int dc = 0; dc < 2; ++dc)
            kf[4 + dc] = *reinterpret_cast<const bf16x8*>(
                &Kr[buf][row * 64 + (((dc * 4 + lg) ^ (row & 7)) * 8)]);
          __builtin_amdgcn_s_setprio(1);
          f32x4 sa = {0.f, 0.f, 0.f, 0.f};
#pragma unroll
          for (int dc = 0; dc < 6; ++dc) sa = mfma16(kf[dc], qf[dc], sa);
          sacc[kb] = sa;
          __builtin_amdgcn_s_setprio(0);
        }
        float sv[4][4];
        if (kbase + 63 <= q0 + w * 16) {  // fully unmasked tile
#pragma unroll
          for (int kb = 0; kb < 4; ++kb)
#pragma unroll
            for (int r = 0; r < 4; ++r) sv[kb][r] = sacc[kb][r];
        } else {
#pragma unroll
          for (int kb = 0; kb < 4; ++kb)
#pragma unroll
            for (int r = 0; r < 4; ++r) {
              int kgl = kbase + kb * 16 + lg * 4 + r;
              sv[kb][r] = (kgl <= qg) ? sacc[kb][r] : -1e30f;
            }
        }
        float pmax = -1e30f;
#pragma unroll
        for (int kb = 0; kb < 4; ++kb)
#pragma unroll
          for (int r = 0; r < 4; ++r) pmax = fmaxf(pmax, sv[kb][r]);
        pmax = fmaxf(pmax, __shfl_xor(pmax, 16));
        pmax = fmaxf(pmax, __shfl_xor(pmax, 32));
        if (!__all(pmax - m_run <= 8.0f)) {  // T13 defer-max
          float mnew = fmaxf(m_run, pmax);
          float alpha = exp2f(m_run - mnew);
          l_run *= alpha;
#pragma unroll
          for (int vb = 0; vb < 8; ++vb) {
            oacc[vb][0] *= alpha; oacc[vb][1] *= alpha;
            oacc[vb][2] *= alpha; oacc[vb][3] *= alpha;
          }
          m_run = mnew;
        }
        float ls = 0.f;
#pragma unroll
        for (int kb = 0; kb < 4; ++kb) {
          bf16x4v pw;
#pragma unroll
          for (int r = 0; r < 4; ++r) {
            float p = exp2f(sv[kb][r] - m_run);
            ls += p;
            pw[r] = (bf16)p;
          }
          *reinterpret_cast<bf16x4v*>(
              &Ps[w * 1024 + lr * 64 +
                  (((kb * 2 + (lg >> 1)) ^ (lr & 7)) * 8) + (lg & 1) * 4]) = pw;
        }
        ls += __shfl_xor(ls, 16);
        ls += __shfl_xor(ls, 32);
        l_run += ls;
#pragma unroll
        for (int c = 0; c < 2; ++c) {
          bf16x8 pb = *reinterpret_cast<const bf16x8*>(
              &Ps[w * 1024 + lr * 64 + (((c * 4 + lg) ^ (lr & 7)) * 8)]);
          __builtin_amdgcn_s_setprio(1);
#pragma unroll
          for (int vb = 0; vb < 8; ++vb) {
            bf16x8 av = *reinterpret_cast<const bf16x8*>(
                &Vs[buf][((c * 8 + vb) * 4 + lg) * 128 + (lr ^ lg) * 8]);
            oacc[vb] = mfma16(av, pb, oacc[vb]);
          }
          __builtin_amdgcn_s_setprio(0);
        }
      }
      if (more) write_vs(buf ^ 1);
      __syncthreads();
    }

    bf16* Os = &Kn[0][0] + w * 2048;
    {
      float inv = 1.0f / l_run;
#pragma unroll
      for (int vb = 0; vb < 8; ++vb) {
        bf16x4v ov;
#pragma unroll
        for (int r = 0; r < 4; ++r) ov[r] = (bf16)(oacc[vb][r] * inv);
        int slot16 = vb * 2 + (lg >> 1);
        *reinterpret_cast<bf16x4v*>(
            &Os[lr * 128 + ((slot16 ^ (lr & 7)) * 8) + (lg & 1) * 4]) = ov;
      }
    }
    asm volatile("s_waitcnt lgkmcnt(0)");
    __builtin_amdgcn_sched_barrier(0);
#pragma unroll
    for (int i = 0; i < 4; ++i) {
      const int r = i * 4 + lg;
      bf16x8 ov = *reinterpret_cast<const bf16x8*>(
          &Os[r * 128 + ((lr ^ (r & 7)) * 8)]);
      *reinterpret_cast<bf16x8*>(
          o + (rowbase + q0 + w * 16 + r) * 2048 + h * 128 + lr * 8) = ov;
    }
    __syncthreads();
  }
}

// ---------------- launch ----------------
extern "C" void kernel_launch(void* const* d_in, const int* in_sizes, int n_in,
                              void* d_out, int out_size, void* d_ws,
                              size_t ws_size, hipStream_t stream) {
  (void)in_sizes; (void)n_in; (void)out_size; (void)ws_size;
  const float* x       = (const float*)d_in[0];
  const float* q_a_w   = (const float*)d_in[1];
  const float* q_a_ln  = (const float*)d_in[2];
  const float* q_b_w   = (const float*)d_in[3];
  const float* kv_a_w  = (const float*)d_in[4];
  const float* kv_a_ln = (const float*)d_in[5];
  const float* kv_b_w  = (const float*)d_in[6];
  const float* o_w     = (const float*)d_in[7];

  char* ws = (char*)d_ws;
  size_t off = 0;
  auto alloc = [&](size_t bytes) {
    void* p = ws + off;
    off += (bytes + 255) & ~(size_t)255;
    return p;
  };
  bf16* x_bf   = (bf16*)alloc((size_t)MR * 2048 * 2);
  bf16* ab_wt  = (bf16*)alloc((size_t)2304 * 2048 * 2);  // [q_a; kv_a; 0pad]^T
  bf16* qb_wt  = (bf16*)alloc((size_t)3072 * 1536 * 2);
  bf16* kvb_wt = (bf16*)alloc((size_t)4096 * 512 * 2);
  bf16* o_wt   = (bf16*)alloc((size_t)2048 * 2048 * 2);
  float* rt    = (float*)alloc((size_t)2048 * 64 * 4);
  bf16* qac    = (bf16*)alloc((size_t)MR * 2304 * 2);  // fused q_a|ckv|pad
  bf16* q_a_n  = (bf16*)alloc((size_t)MR * 1536 * 2);
  bf16* kv_c_n = (bf16*)alloc((size_t)MR * 512 * 2);
  bf16* kr     = (bf16*)alloc((size_t)MR * 64 * 2);
  bf16* qbuf   = (bf16*)alloc((size_t)MR * 3072 * 2);
  bf16* kvbuf  = (bf16*)alloc((size_t)MR * 4096 * 2);
  bf16* attn_o = (bf16*)alloc((size_t)MR * 2048 * 2);

  k_prep<<<PREP_BLOCKS, 256, 0, stream>>>(x, q_a_w, kv_a_w, q_b_w, kv_b_w,
                                          o_w, x_bf, ab_wt, qb_wt, kvb_wt,
                                          o_wt, rt);
  // fused q_a + kv_a down-projection: 128x128 tiles, 2 blocks/CU (576 blocks)
  k_gemm2s<false><<<dim3(18, 32), 512, 0, stream>>>(x_bf, ab_wt, qac, 2304,
                                                    2048);
  k_norms<<<MR, 64, 0, stream>>>(qac, q_a_ln, kv_a_ln, rt, q_a_n, kv_c_n, kr);
  // q_b + kv_b on 256x128 tiles: 896 blocks, near-ideal greedy packing
  k_gemm4n_dual<<<dim3(896), 512, 0, stream>>>(q_a_n, qb_wt, qbuf, kv_c_n,
                                               kvb_wt, kvbuf);
  k_attn<<<dim3(256), 512, 0, stream>>>(qbuf, kvbuf, kr, rt, attn_o);
  // o-projection: BN=128 variant -> 256 blocks (full CU coverage)
  k_gemm4n<true><<<dim3(16, 16), 512, 0, stream>>>(attn_o, o_wt, d_out, 2048,
                                                   2048);
}

// Round 20
// 255.621 us; speedup vs baseline: 1.0239x; 1.0239x over previous
//
#include <hip/hip_runtime.h>
#include <hip/hip_bf16.h>
#include <cstdint>

// MLA: B=2, T=2048, H=16, d_nope=128, d_rope=64, d_qk=192, d_v=128,
// kv_lora=512, q_lora=1536, hidden=2048. Output f32 [4096][2048].

typedef __bf16 bf16;
typedef __bf16 bf16x8 __attribute__((ext_vector_type(8)));
typedef __bf16 bf16x4v __attribute__((ext_vector_type(4)));
typedef float f32x4 __attribute__((ext_vector_type(4)));

#define TSEQ 2048
#define MR 4096  // B*T

typedef const uint32_t __attribute__((address_space(1))) * gas1_t;
typedef uint32_t __attribute__((address_space(3))) * las3_t;

static __device__ __forceinline__ void gload_lds16(const void* g, void* l) {
  __builtin_amdgcn_global_load_lds(
      reinterpret_cast<gas1_t>(reinterpret_cast<uintptr_t>(g)),
      reinterpret_cast<las3_t>(reinterpret_cast<uintptr_t>(l)), 16, 0, 0);
}

static __device__ __forceinline__ f32x4 mfma16(bf16x8 a, bf16x8 b, f32x4 c) {
  return __builtin_amdgcn_mfma_f32_16x16x32_bf16(a, b, c, 0, 0, 0);
}

// ---------------- fused prep kernel (proven round 11) ----------------------
static __device__ __forceinline__ void do_transpose(
    const float* __restrict__ W, bf16* __restrict__ Wt, int K, int N, int bi,
    int bj, float (*t)[33]) {
  int c = threadIdx.x & 31, r0 = threadIdx.x >> 5;
#pragma unroll
  for (int rr = 0; rr < 32; rr += 8)
    t[rr + r0][c] = W[(size_t)(bj * 32 + rr + r0) * N + bi * 32 + c];
  __syncthreads();
#pragma unroll
  for (int rr = 0; rr < 32; rr += 8)
    Wt[(size_t)(bi * 32 + rr + r0) * K + bj * 32 + c] = (bf16)t[c][rr + r0];
}

#define PREP_BLOCKS (8192 + 3072 + 1152 + 4608 + 2048 + 4096 + 192 + 256)

__global__ __launch_bounds__(256) void k_prep(
    const float* __restrict__ x, const float* __restrict__ q_a_w,
    const float* __restrict__ kv_a_w, const float* __restrict__ q_b_w,
    const float* __restrict__ kv_b_w, const float* __restrict__ o_w,
    bf16* __restrict__ x_bf, bf16* __restrict__ ab_wt,
    bf16* __restrict__ qb_wt, bf16* __restrict__ kvb_wt,
    bf16* __restrict__ o_wt, float* __restrict__ rt) {
  __shared__ float t[32][33];
  int nb = blockIdx.x;
  const int tid = threadIdx.x;
  if (nb < 8192) {  // cvt x -> bf16
    int i = nb * 256 + tid;
    float4 f = reinterpret_cast<const float4*>(x)[i];
    bf16x4v o = {(bf16)f.x, (bf16)f.y, (bf16)f.z, (bf16)f.w};
    reinterpret_cast<bf16x4v*>(x_bf)[i] = o;
    return;
  }
  nb -= 8192;
  if (nb < 3072) { do_transpose(q_a_w, ab_wt, 2048, 1536, nb % 48, nb / 48, t); return; }
  nb -= 3072;
  if (nb < 1152) {
    do_transpose(kv_a_w, ab_wt + (size_t)1536 * 2048, 2048, 576, nb % 18, nb / 18, t);
    return;
  }
  nb -= 1152;
  if (nb < 4608) { do_transpose(q_b_w, qb_wt, 1536, 3072, nb % 96, nb / 96, t); return; }
  nb -= 4608;
  if (nb < 2048) { do_transpose(kv_b_w, kvb_wt, 512, 4096, nb % 128, nb / 128, t); return; }
  nb -= 2048;
  if (nb < 4096) { do_transpose(o_w, o_wt, 2048, 2048, nb % 64, nb / 64, t); return; }
  nb -= 4096;
  if (nb < 192) {  // zero-fill pad rows 2112..2303 of ab_wt
    uint4 z = make_uint4(0, 0, 0, 0);
    reinterpret_cast<uint4*>(ab_wt + (size_t)2112 * 2048)[nb * 256 + tid] = z;
    return;
  }
  nb -= 192;
  {  // rope table: rt[t][2j]={cos}, [2j+1]={sin}
    int idx = nb * 256 + tid;
    int tt = idx >> 5, j = idx & 31;
    float freq = exp2f(-(float)j * (1.0f / 32.0f) * log2f(500000.0f));
    float ang = (float)tt * freq;
    rt[tt * 64 + 2 * j] = cosf(ang);
    rt[tt * 64 + 2 * j + 1] = sinf(ang);
  }
}

// ---------------- fused norms: q-rmsnorm + kv-rmsnorm + k-rope -------------
__global__ __launch_bounds__(64) void k_norms(
    const bf16* __restrict__ qac, const float* __restrict__ qw,
    const float* __restrict__ kvw, const float* __restrict__ rt,
    bf16* __restrict__ q_a_n, bf16* __restrict__ kv_c_n,
    bf16* __restrict__ kr) {
  int row = blockIdx.x, lane = threadIdx.x;
  const bf16* ip = qac + (size_t)row * 2304;
  bf16x8 v[3];
  float ss = 0.f;
#pragma unroll
  for (int c = 0; c < 3; ++c) {
    v[c] = *reinterpret_cast<const bf16x8*>(ip + c * 512 + lane * 8);
#pragma unroll
    for (int e = 0; e < 8; ++e) { float f = (float)v[c][e]; ss += f * f; }
  }
#pragma unroll
  for (int m = 1; m <= 32; m <<= 1) ss += __shfl_xor(ss, m);
  float rs = rsqrtf(ss / 1536.0f + 1e-6f);
  bf16* op = q_a_n + (size_t)row * 1536;
#pragma unroll
  for (int c = 0; c < 3; ++c) {
    bf16x8 o;
#pragma unroll
    for (int e = 0; e < 8; ++e)
      o[e] = (bf16)((float)v[c][e] * rs * qw[c * 512 + lane * 8 + e]);
    *reinterpret_cast<bf16x8*>(op + c * 512 + lane * 8) = o;
  }
  bf16x8 kvv = *reinterpret_cast<const bf16x8*>(ip + 1536 + lane * 8);
  float s2 = 0.f;
#pragma unroll
  for (int e = 0; e < 8; ++e) { float f = (float)kvv[e]; s2 += f * f; }
#pragma unroll
  for (int m = 1; m <= 32; m <<= 1) s2 += __shfl_xor(s2, m);
  float rs2 = rsqrtf(s2 / 512.0f + 1e-6f);
  bf16x8 o2;
#pragma unroll
  for (int e = 0; e < 8; ++e)
    o2[e] = (bf16)((float)kvv[e] * rs2 * kvw[lane * 8 + e]);
  *reinterpret_cast<bf16x8*>(kv_c_n + (size_t)row * 512 + lane * 8) = o2;
  if (lane < 32) {
    int t = row & (TSEQ - 1);
    float x0 = (float)ip[2048 + 2 * lane], x1 = (float)ip[2048 + 2 * lane + 1];
    float c = rt[t * 64 + 2 * lane], s = rt[t * 64 + 2 * lane + 1];
    kr[(size_t)row * 64 + lane] = (bf16)(x0 * c - x1 * s);
    kr[(size_t)row * 64 + 32 + lane] = (bf16)(x1 * c + x0 * s);
  }
}

// ---------------- 8-phase 256x256 GEMM body (T2+T3+T4+T5) ------------------
#define GPH(BUF, MH, KH, DO_READB, STAGE_STMT, WAIT_STMT)                     \
  {                                                                           \
    if (DO_READB) {                                                           \
      _Pragma("unroll") for (int ni = 0; ni < 4; ++ni) {                      \
        int row = wn * 64 + ni * 16 + lr;                                     \
        breg[KH][ni] = *reinterpret_cast<const bf16x8*>(                      \
            &Bs[BUF][row * 64 + ((((KH)*4 + lg) ^ (row & 7)) * 8)]);          \
      }                                                                       \
    }                                                                         \
    bf16x8 af[4];                                                             \
    _Pragma("unroll") for (int mi = 0; mi < 4; ++mi) {                        \
      int row = wm * 128 + (MH)*64 + mi * 16 + lr;                            \
      af[mi] = *reinterpret_cast<const bf16x8*>(                              \
          &As[BUF][row * 64 + ((((KH)*4 + lg) ^ (row & 7)) * 8)]);            \
    }                                                                         \
    STAGE_STMT;                                                               \
    __builtin_amdgcn_s_barrier();                                             \
    __builtin_amdgcn_s_setprio(1);                                            \
    _Pragma("unroll") for (int mi = 0; mi < 4; ++mi)                          \
        _Pragma("unroll") for (int ni = 0; ni < 4; ++ni)                      \
            acc[(MH)*4 + mi][ni] =                                            \
        mfma16(af[mi], breg[KH][ni], acc[(MH)*4 + mi][ni]);                   \
    __builtin_amdgcn_s_setprio(0);                                            \
    WAIT_STMT;                                                                \
    __builtin_amdgcn_s_barrier();                                             \
  }

template <bool OUT_F32>
static __device__ __forceinline__ void gemm8_body(
    const bf16* __restrict__ A, const bf16* __restrict__ Bt,
    void* __restrict__ C, int N, int K, int bi, int bj, bf16 (*As)[16384],
    bf16 (*Bs)[16384]) {
  const int tid = threadIdx.x, lane = tid & 63, w = tid >> 6;
  const int lg = lane >> 4, lr = lane & 15;
  const int wm = w >> 2, wn = w & 3;
  const int m0 = bj * 256, n0 = bi * 256;
  const int T = K >> 7;

  f32x4 acc[8][4] = {};
  bf16x8 breg[2][4];

  auto stageA = [&](int tau, int h) {
    char* dst = (char*)&As[tau & 1][0] + h * 16384;
#pragma unroll
    for (int j = 0; j < 2; ++j) {
      int c = j * 512 + tid;
      int row = c >> 3, slot = c & 7;
      gload_lds16(A + (size_t)(m0 + h * 128 + row) * K + tau * 64 +
                      ((slot ^ (row & 7)) * 8),
                  dst + (size_t)(j * 512 + w * 64) * 16);
    }
  };
  auto stageB = [&](int tau, int h) {
    char* dst = (char*)&Bs[tau & 1][0] + h * 16384;
#pragma unroll
    for (int j = 0; j < 2; ++j) {
      int c = j * 512 + tid;
      int row = c >> 3, slot = c & 7;
      gload_lds16(Bt + (size_t)(n0 + h * 128 + row) * K + tau * 64 +
                      ((slot ^ (row & 7)) * 8),
                  dst + (size_t)(j * 512 + w * 64) * 16);
    }
  };

  stageB(0, 0); stageB(0, 1); stageA(0, 0); stageA(0, 1);
  stageB(1, 0); stageB(1, 1); stageA(1, 0);
  asm volatile("s_waitcnt vmcnt(6)" ::: "memory");
  __builtin_amdgcn_s_barrier();

  for (int t = 0; t < T - 1; ++t) {
    const int s2 = 2 * t + 2, s3 = 2 * t + 3, a1 = 2 * t + 1;
    GPH(0, 0, 0, true,  stageA(a1, 1), ((void)0));
    GPH(0, 0, 1, true,  stageB(s2, 0), ((void)0));
    GPH(0, 1, 0, false, stageB(s2, 1), ((void)0));
    GPH(0, 1, 1, false, stageA(s2, 0),
        asm volatile("s_waitcnt vmcnt(6)" ::: "memory"));
    GPH(1, 0, 0, true,  stageA(s2, 1), ((void)0));
    GPH(1, 0, 1, true,  stageB(s3, 0), ((void)0));
    GPH(1, 1, 0, false, stageB(s3, 1), ((void)0));
    GPH(1, 1, 1, false, stageA(s3, 0),
        asm volatile("s_waitcnt vmcnt(6)" ::: "memory"));
  }
  {
    const int a1 = 2 * T - 1;
    GPH(0, 0, 0, true,  stageA(a1, 1), ((void)0));
    GPH(0, 0, 1, true,  ((void)0),     ((void)0));
    GPH(0, 1, 0, false, ((void)0),     ((void)0));
    GPH(0, 1, 1, false, ((void)0),
        asm volatile("s_waitcnt vmcnt(0)" ::: "memory"));
    GPH(1, 0, 0, true,  ((void)0), ((void)0));
    GPH(1, 0, 1, true,  ((void)0), ((void)0));
    GPH(1, 1, 0, false, ((void)0), ((void)0));
    GPH(1, 1, 1, false, ((void)0), ((void)0));
  }

#pragma unroll
  for (int mi = 0; mi < 8; ++mi)
#pragma unroll
    for (int ni = 0; ni < 4; ++ni) {
      int col = n0 + wn * 64 + ni * 16 + lr;
#pragma unroll
      for (int r = 0; r < 4; ++r) {
        int rowg = m0 + wm * 128 + mi * 16 + lg * 4 + r;
        if (OUT_F32)
          reinterpret_cast<float*>(C)[(size_t)rowg * N + col] = acc[mi][ni][r];
        else
          reinterpret_cast<bf16*>(C)[(size_t)rowg * N + col] =
              (bf16)acc[mi][ni][r];
      }
    }
}

// q_b (192 blocks, T=12, issued first) co-dispatched with kv_b (256, T=4)
__global__ __launch_bounds__(512, 2) void k_gemm8_dual(
    const bf16* __restrict__ A1, const bf16* __restrict__ B1,
    bf16* __restrict__ C1, const bf16* __restrict__ A2,
    const bf16* __restrict__ B2, bf16* __restrict__ C2) {
  __shared__ bf16 As[2][16384];
  __shared__ bf16 Bs[2][16384];
  int id = blockIdx.x;
  if (id < 192) {
    int wg = (id & 7) * 24 + (id >> 3);
    gemm8_body<false>(A1, B1, C1, 3072, 1536, wg % 12, wg / 12, As, Bs);
  } else {
    int s = id - 192;
    int wg = (s & 7) * 32 + (s >> 3);
    gemm8_body<false>(A2, B2, C2, 4096, 512, wg % 16, wg / 16, As, Bs);
  }
}

// ---------- 4-phase 256x128 GEMM (BN=128): full CU fill for o-proj ---------
#define GPN(BUF, KH, STAGE_STMT, WAIT_STMT)                                   \
  {                                                                           \
    bf16x8 bfr[4];                                                            \
    _Pragma("unroll") for (int ni = 0; ni < 4; ++ni) {                        \
      int row = wn * 64 + ni * 16 + lr;                                       \
      bfr[ni] = *reinterpret_cast<const bf16x8*>(                             \
          &Bs[BUF][row * 64 + ((((KH)*4 + lg) ^ (row & 7)) * 8)]);            \
    }                                                                         \
    bf16x8 af[4];                                                             \
    _Pragma("unroll") for (int mi = 0; mi < 4; ++mi) {                        \
      int row = wm * 64 + mi * 16 + lr;                                       \
      af[mi] = *reinterpret_cast<const bf16x8*>(                              \
          &As[BUF][row * 64 + ((((KH)*4 + lg) ^ (row & 7)) * 8)]);            \
    }                                                                         \
    STAGE_STMT;                                                               \
    __builtin_amdgcn_s_barrier();                                             \
    __builtin_amdgcn_s_setprio(1);                                            \
    _Pragma("unroll") for (int mi = 0; mi < 4; ++mi)                          \
        _Pragma("unroll") for (int ni = 0; ni < 4; ++ni)                      \
            acc[mi][ni] = mfma16(af[mi], bfr[ni], acc[mi][ni]);               \
    __builtin_amdgcn_s_setprio(0);                                            \
    WAIT_STMT;                                                                \
    __builtin_amdgcn_s_barrier();                                             \
  }

template <bool OUT_F32>
__global__ __launch_bounds__(512, 2) void k_gemm4n(const bf16* __restrict__ A,
                                                   const bf16* __restrict__ Bt,
                                                   void* __restrict__ C, int N,
                                                   int K) {
  __shared__ bf16 As[2][16384];  // 256 rows x 64 k
  __shared__ bf16 Bs[2][8192];   // 128 rows x 64 k
  const int tid = threadIdx.x, lane = tid & 63, w = tid >> 6;
  const int lg = lane >> 4, lr = lane & 15;
  const int wm = w >> 1, wn = w & 1;
  const int nwg = gridDim.x * gridDim.y;
  const int orig = blockIdx.y * gridDim.x + blockIdx.x;
  const int wgid = (orig & 7) * (nwg >> 3) + (orig >> 3);
  const int m0 = (wgid / gridDim.x) * 256, n0 = (wgid % gridDim.x) * 128;
  const int T = K >> 7;

  f32x4 acc[4][4] = {};

  auto stA = [&](int tau, int h) {
    char* dst = (char*)&As[tau & 1][0] + h * 16384;
#pragma unroll
    for (int j = 0; j < 2; ++j) {
      int c = j * 512 + tid;
      int row = c >> 3, slot = c & 7;
      gload_lds16(A + (size_t)(m0 + h * 128 + row) * K + tau * 64 +
                      ((slot ^ (row & 7)) * 8),
                  dst + (size_t)(j * 512 + w * 64) * 16);
    }
  };
  auto stB = [&](int tau) {
    char* dst = (char*)&Bs[tau & 1][0];
#pragma unroll
    for (int j = 0; j < 2; ++j) {
      int c = j * 512 + tid;
      int row = c >> 3, slot = c & 7;
      gload_lds16(Bt + (size_t)(n0 + row) * K + tau * 64 +
                      ((slot ^ (row & 7)) * 8),
                  dst + (size_t)(j * 512 + w * 64) * 16);
    }
  };

  stA(0, 0); stA(0, 1); stB(0); stA(1, 0);
  asm volatile("s_waitcnt vmcnt(2)" ::: "memory");
  __builtin_amdgcn_s_barrier();

  for (int t = 0; t < T - 1; ++t) {
    const int u1 = 2 * t + 1, s2 = 2 * t + 2, s3 = 2 * t + 3;
    GPN(0, 0, stA(u1, 1), ((void)0));
    GPN(0, 1, { stB(u1); stA(s2, 0); },
        asm volatile("s_waitcnt vmcnt(2)" ::: "memory"));
    GPN(1, 0, stA(s2, 1), ((void)0));
    GPN(1, 1, { stB(s2); stA(s3, 0); },
        asm volatile("s_waitcnt vmcnt(2)" ::: "memory"));
  }
  {
    const int u1 = 2 * T - 1;
    GPN(0, 0, stA(u1, 1), ((void)0));
    GPN(0, 1, stB(u1),
        asm volatile("s_waitcnt vmcnt(0)" ::: "memory"));
    GPN(1, 0, ((void)0), ((void)0));
    GPN(1, 1, ((void)0), ((void)0));
  }

#pragma unroll
  for (int mi = 0; mi < 4; ++mi)
#pragma unroll
    for (int ni = 0; ni < 4; ++ni) {
      int col = n0 + wn * 64 + ni * 16 + lr;
#pragma unroll
      for (int r = 0; r < 4; ++r) {
        int rowg = m0 + wm * 64 + mi * 16 + lg * 4 + r;
        if (OUT_F32)
          reinterpret_cast<float*>(C)[(size_t)rowg * N + col] = acc[mi][ni][r];
        else
          reinterpret_cast<bf16*>(C)[(size_t)rowg * N + col] =
              (bf16)acc[mi][ni][r];
      }
    }
}

// ---------- 4-phase 128x128 GEMM, 64K LDS -> 2 blocks/CU (qac) -------------
#define GPS(BUF, KH, STAGE_STMT, WAIT_STMT)                                   \
  {                                                                           \
    bf16x8 bfr[4];                                                            \
    _Pragma("unroll") for (int ni = 0; ni < 4; ++ni) {                        \
      int row = wc * 64 + ni * 16 + lr;                                       \
      bfr[ni] = *reinterpret_cast<const bf16x8*>(                             \
          &Bs[BUF][row * 64 + ((((KH)*4 + lg) ^ (row & 7)) * 8)]);            \
    }                                                                         \
    bf16x8 af[2];                                                             \
    _Pragma("unroll") for (int mi = 0; mi < 2; ++mi) {                        \
      int row = wr * 32 + mi * 16 + lr;                                       \
      af[mi] = *reinterpret_cast<const bf16x8*>(                              \
          &As[BUF][row * 64 + ((((KH)*4 + lg) ^ (row & 7)) * 8)]);            \
    }                                                                         \
    STAGE_STMT;                                                               \
    __builtin_amdgcn_s_barrier();                                             \
    __builtin_amdgcn_s_setprio(1);                                            \
    _Pragma("unroll") for (int mi = 0; mi < 2; ++mi)                          \
        _Pragma("unroll") for (int ni = 0; ni < 4; ++ni)                      \
            acc[mi][ni] = mfma16(af[mi], bfr[ni], acc[mi][ni]);               \
    __builtin_amdgcn_s_setprio(0);                                            \
    WAIT_STMT;                                                                \
    __builtin_amdgcn_s_barrier();                                             \
  }

template <bool OUT_F32>
__global__ __launch_bounds__(512, 2) void k_gemm2s(const bf16* __restrict__ A,
                                                   const bf16* __restrict__ Bt,
                                                   void* __restrict__ C, int N,
                                                   int K) {
  __shared__ bf16 As[2][8192];  // 128 rows x 64 k
  __shared__ bf16 Bs[2][8192];  // 128 rows x 64 k
  const int tid = threadIdx.x, lane = tid & 63, w = tid >> 6;
  const int lg = lane >> 4, lr = lane & 15;
  const int wr = w >> 1, wc = w & 1;
  const int nwg = gridDim.x * gridDim.y;
  const int orig = blockIdx.y * gridDim.x + blockIdx.x;
  const int wgid = (orig & 7) * (nwg >> 3) + (orig >> 3);
  const int m0 = (wgid / gridDim.x) * 128, n0 = (wgid % gridDim.x) * 128;
  const int T = K >> 7;

  f32x4 acc[2][4] = {};

  auto stA = [&](int tau) {
    char* dst = (char*)&As[tau & 1][0];
#pragma unroll
    for (int j = 0; j < 2; ++j) {
      int c = j * 512 + tid;
      int row = c >> 3, slot = c & 7;
      gload_lds16(A + (size_t)(m0 + row) * K + tau * 64 +
                      ((slot ^ (row & 7)) * 8),
                  dst + (size_t)(j * 512 + w * 64) * 16);
    }
  };
  auto stB = [&](int tau) {
    char* dst = (char*)&Bs[tau & 1][0];
#pragma unroll
    for (int j = 0; j < 2; ++j) {
      int c = j * 512 + tid;
      int row = c >> 3, slot = c & 7;
      gload_lds16(Bt + (size_t)(n0 + row) * K + tau * 64 +
                      ((slot ^ (row & 7)) * 8),
                  dst + (size_t)(j * 512 + w * 64) * 16);
    }
  };

  stA(0); stB(0); stA(1);
  asm volatile("s_waitcnt vmcnt(2)" ::: "memory");
  __builtin_amdgcn_s_barrier();

  for (int t = 0; t < T - 1; ++t) {
    const int u1 = 2 * t + 1, s2 = 2 * t + 2, s3 = 2 * t + 3;
    GPS(0, 0, stB(u1), ((void)0));
    GPS(0, 1, stA(s2),
        asm volatile("s_waitcnt vmcnt(2)" ::: "memory"));
    GPS(1, 0, stB(s2), ((void)0));
    GPS(1, 1, stA(s3),
        asm volatile("s_waitcnt vmcnt(2)" ::: "memory"));
  }
  {
    const int u1 = 2 * T - 1;
    GPS(0, 0, stB(u1), ((void)0));
    GPS(0, 1, ((void)0),
        asm volatile("s_waitcnt vmcnt(0)" ::: "memory"));
    GPS(1, 0, ((void)0), ((void)0));
    GPS(1, 1, ((void)0), ((void)0));
  }

#pragma unroll
  for (int mi = 0; mi < 2; ++mi)
#pragma unroll
    for (int ni = 0; ni < 4; ++ni) {
      int col = n0 + wc * 64 + ni * 16 + lr;
#pragma unroll
      for (int r = 0; r < 4; ++r) {
        int rowg = m0 + wr * 32 + mi * 16 + lg * 4 + r;
        if (OUT_F32)
          reinterpret_cast<float*>(C)[(size_t)rowg * N + col] = acc[mi][ni][r];
        else
          reinterpret_cast<bf16*>(C)[(size_t)rowg * N + col] =
              (bf16)acc[mi][ni][r];
      }
    }
}

// ---------------- causal flash attention v6r (round-16, known-good) --------
__global__ __launch_bounds__(512, 2) void k_attn(const bf16* __restrict__ q,
                                                 const bf16* __restrict__ kv,
                                                 const bf16* __restrict__ kr,
                                                 const float* __restrict__ rt,
                                                 bf16* __restrict__ o) {
  __shared__ bf16 Kn[2][64 * 128];  // linear chunks; data col = j^(row&15)
  __shared__ bf16 Kr[2][64 * 64];   // data col = j^(row&7)
  __shared__ bf16 Vs[2][64 * 128];  // fragment-packed V^T
  __shared__ bf16 Ps[8 * 1024];     // per-wave P [16 q][64 k] swizzled
  const int tid = threadIdx.x, lane = tid & 63, w = tid >> 6;
  const int lg = lane >> 4, lr = lane & 15;
  const float qsc = 0.07216878364870323f * 1.44269504088896f;  // 192^-.5*log2e
  uint4 vreg[2];
  const int vrr = tid & 31, vvc = tid >> 5;

  for (int t = 0; t < 2; ++t) {
    const int id = t ? 511 - (int)blockIdx.x : (int)blockIdx.x;
    const int qt = 15 - (id >> 5);
    const int bh = id & 31;
    const int b = bh >> 4, h = bh & 15;
    const int q0 = qt * 128;
    const size_t rowbase = (size_t)b * TSEQ;
    const int nkt = 2 * qt + 2;
    const int qg = q0 + w * 16 + lr;

    auto issue_loads = [&](int kbase, int buf) {
#pragma unroll
      for (int kk = 0; kk < 2; ++kk)
        vreg[kk] = *reinterpret_cast<const uint4*>(
            kv + (rowbase + kbase + vrr * 2 + kk) * 4096 + h * 256 + 128 +
            vvc * 8);
#pragma unroll
      for (int i = 0; i < 2; ++i) {
        int c = i * 512 + tid;
        int row = c >> 4, j = c & 15;
        gload_lds16(
            kv + (rowbase + kbase + row) * 4096 + h * 256 +
                ((j ^ (row & 15)) * 8),
            (char*)&Kn[buf][0] + (size_t)(i * 512 + w * 64) * 16);
      }
      {
        int row = tid >> 3, j = tid & 7;
        gload_lds16(kr + (rowbase + kbase + row) * 64 + ((j ^ (row & 7)) * 8),
                    (char*)&Kr[buf][0] + (size_t)(w * 64) * 16);
      }
    };

    auto write_vs = [&](int buf) {
      const int kb0 = vrr * 2;
      const int cC = kb0 >> 5, g = (kb0 >> 3) & 3, j0 = kb0 & 7;
      const uint32_t* r0 = reinterpret_cast<const uint32_t*>(&vreg[0]);
      const uint32_t* r1 = reinterpret_cast<const uint32_t*>(&vreg[1]);
#pragma unroll
      for (int e = 0; e < 8; ++e) {
        uint32_t h0 = (r0[e >> 1] >> ((e & 1) * 16)) & 0xffffu;
        uint32_t h1 = (r1[e >> 1] >> ((e & 1) * 16)) & 0xffffu;
        int vd = vvc * 8 + e;
        int slot = (vd & 15) ^ g;
        *reinterpret_cast<uint32_t*>(
            &Vs[buf][((cC * 8 + (vd >> 4)) * 4 + g) * 128 + slot * 8 + j0]) =
            h0 | (h1 << 16);
      }
    };

    // Q fragments: nope cols direct; rope cols computed in-register from rt.
    bf16x8 qf[6];
    {
      const bf16* qp = q + (rowbase + qg) * 3072 + h * 192;
#pragma unroll
      for (int dc = 0; dc < 4; ++dc) {
        bf16x8 v = *reinterpret_cast<const bf16x8*>(qp + dc * 32 + lg * 8);
#pragma unroll
        for (int e = 0; e < 8; ++e) v[e] = (bf16)((float)v[e] * qsc);
        qf[dc] = v;
      }
      bf16x8 ra = *reinterpret_cast<const bf16x8*>(qp + 128 + lg * 16);
      bf16x8 rb = *reinterpret_cast<const bf16x8*>(qp + 128 + lg * 16 + 8);
      const float* rtp = rt + (size_t)qg * 64 + lg * 16;
      float4 r0 = *reinterpret_cast<const float4*>(rtp);
      float4 r1 = *reinterpret_cast<const float4*>(rtp + 4);
      float4 r2 = *reinterpret_cast<const float4*>(rtp + 8);
      float4 r3 = *reinterpret_cast<const float4*>(rtp + 12);
      float rc[8] = {r0.x, r0.z, r1.x, r1.z, r2.x, r2.z, r3.x, r3.z};
      float rs_[8] = {r0.y, r0.w, r1.y, r1.w, r2.y, r2.w, r3.y, r3.w};
      bf16x8 v4, v5;
#pragma unroll
      for (int j = 0; j < 8; ++j) {
        float x0 = (float)((j < 4) ? ra[2 * j] : rb[2 * j - 8]);
        float x1 = (float)((j < 4) ? ra[2 * j + 1] : rb[2 * j - 7]);
        v4[j] = (bf16)((x0 * rc[j] - x1 * rs_[j]) * qsc);
        v5[j] = (bf16)((x1 * rc[j] + x0 * rs_[j]) * qsc);
      }
      qf[4] = v4;
      qf[5] = v5;
    }

    f32x4 oacc[8] = {};
    float m_run = -1e30f, l_run = 0.f;

    issue_loads(0, 0);
    write_vs(0);
    __syncthreads();

    for (int kt = 0; kt < nkt; ++kt) {
      const int kbase = kt * 64;
      const int buf = kt & 1;
      const bool more = (kt + 1 < nkt);
      if (more) issue_loads(kbase + 64, buf ^ 1);

      if (kbase <= q0 + w * 16 + 15) {
        f32x4 sacc[4];
#pragma unroll
        for (int kb = 0; kb < 4; ++kb) {
          const int row = kb * 16 + lr;
          bf16x8 kf[6];
#pragma unroll
          for (int dc = 0; dc < 4; ++dc)
            kf[dc] = *reinterpret_cast<const bf16x8*>(
                &Kn[buf][row * 128 + (((dc * 4 + lg) ^ (row & 15)) * 8)]);
#pragma unroll
          for (int dc = 0; dc < 2; ++dc)
            kf[4 + dc] = *reinterpret_cast<const bf16x8*>(
                &Kr[buf][row * 64 + (((dc * 4 + lg) ^ (row & 7)) * 8)]);
          __builtin_amdgcn_s_setprio(1);
          f32x4 sa = {0.f, 0.f, 0.f, 0.f};
#pragma unroll
          for (int dc = 0; dc < 6; ++dc) sa = mfma16(kf[dc], qf[dc], sa);
          sacc[kb] = sa;
          __builtin_amdgcn_s_setprio(0);
        }
        float sv[4][4];
        if (kbase + 63 <= q0 + w * 16) {  // fully unmasked tile
#pragma unroll
          for (int kb = 0; kb < 4; ++kb)
#pragma unroll
            for (int r = 0; r < 4; ++r) sv[kb][r] = sacc[kb][r];
        } else {
#pragma unroll
          for (int kb = 0; kb < 4; ++kb)
#pragma unroll
            for (int r = 0; r < 4; ++r) {
              int kgl = kbase + kb * 16 + lg * 4 + r;
              sv[kb][r] = (kgl <= qg) ? sacc[kb][r] : -1e30f;
            }
        }
        float pmax = -1e30f;
#pragma unroll
        for (int kb = 0; kb < 4; ++kb)
#pragma unroll
          for (int r = 0; r < 4; ++r) pmax = fmaxf(pmax, sv[kb][r]);
        pmax = fmaxf(pmax, __shfl_xor(pmax, 16));
        pmax = fmaxf(pmax, __shfl_xor(pmax, 32));
        if (!__all(pmax - m_run <= 8.0f)) {  // T13 defer-max
          float mnew = fmaxf(m_run, pmax);
          float alpha = exp2f(m_run - mnew);
          l_run *= alpha;
#pragma unroll
          for (int vb = 0; vb < 8; ++vb) {
            oacc[vb][0] *= alpha; oacc[vb][1] *= alpha;
            oacc[vb][2] *= alpha; oacc[vb][3] *= alpha;
          }
          m_run = mnew;
        }
        float ls = 0.f;
#pragma unroll
        for (int kb = 0; kb < 4; ++kb) {
          bf16x4v pw;
#pragma unroll
          for (int r = 0; r < 4; ++r) {
            float p = exp2f(sv[kb][r] - m_run);
            ls += p;
            pw[r] = (bf16)p;
          }
          *reinterpret_cast<bf16x4v*>(
              &Ps[w * 1024 + lr * 64 +
                  (((kb * 2 + (lg >> 1)) ^ (lr & 7)) * 8) + (lg & 1) * 4]) = pw;
        }
        ls += __shfl_xor(ls, 16);
        ls += __shfl_xor(ls, 32);
        l_run += ls;
#pragma unroll
        for (int c = 0; c < 2; ++c) {
          bf16x8 pb = *reinterpret_cast<const bf16x8*>(
              &Ps[w * 1024 + lr * 64 + (((c * 4 + lg) ^ (lr & 7)) * 8)]);
          __builtin_amdgcn_s_setprio(1);
#pragma unroll
          for (int vb = 0; vb < 8; ++vb) {
            bf16x8 av = *reinterpret_cast<const bf16x8*>(
                &Vs[buf][((c * 8 + vb) * 4 + lg) * 128 + (lr ^ lg) * 8]);
            oacc[vb] = mfma16(av, pb, oacc[vb]);
          }
          __builtin_amdgcn_s_setprio(0);
        }
      }
      if (more) write_vs(buf ^ 1);
      __syncthreads();
    }

    bf16* Os = &Kn[0][0] + w * 2048;
    {
      float inv = 1.0f / l_run;
#pragma unroll
      for (int vb = 0; vb < 8; ++vb) {
        bf16x4v ov;
#pragma unroll
        for (int r = 0; r < 4; ++r) ov[r] = (bf16)(oacc[vb][r] * inv);
        int slot16 = vb * 2 + (lg >> 1);
        *reinterpret_cast<bf16x4v*>(
            &Os[lr * 128 + ((slot16 ^ (lr & 7)) * 8) + (lg & 1) * 4]) = ov;
      }
    }
    asm volatile("s_waitcnt lgkmcnt(0)");
    __builtin_amdgcn_sched_barrier(0);
#pragma unroll
    for (int i = 0; i < 4; ++i) {
      const int r = i * 4 + lg;
      bf16x8 ov = *reinterpret_cast<const bf16x8*>(
          &Os[r * 128 + ((lr ^ (r & 7)) * 8)]);
      *reinterpret_cast<bf16x8*>(
          o + (rowbase + q0 + w * 16 + r) * 2048 + h * 128 + lr * 8) = ov;
    }
    __syncthreads();
  }
}

// ---------------- launch ----------------
extern "C" void kernel_launch(void* const* d_in, const int* in_sizes, int n_in,
                              void* d_out, int out_size, void* d_ws,
                              size_t ws_size, hipStream_t stream) {
  (void)in_sizes; (void)n_in; (void)out_size; (void)ws_size;
  const float* x       = (const float*)d_in[0];
  const float* q_a_w   = (const float*)d_in[1];
  const float* q_a_ln  = (const float*)d_in[2];
  const float* q_b_w   = (const float*)d_in[3];
  const float* kv_a_w  = (const float*)d_in[4];
  const float* kv_a_ln = (const float*)d_in[5];
  const float* kv_b_w  = (const float*)d_in[6];
  const float* o_w     = (const float*)d_in[7];

  char* ws = (char*)d_ws;
  size_t off = 0;
  auto alloc = [&](size_t bytes) {
    void* p = ws + off;
    off += (bytes + 255) & ~(size_t)255;
    return p;
  };
  bf16* x_bf   = (bf16*)alloc((size_t)MR * 2048 * 2);
  bf16* ab_wt  = (bf16*)alloc((size_t)2304 * 2048 * 2);  // [q_a; kv_a; 0pad]^T
  bf16* qb_wt  = (bf16*)alloc((size_t)3072 * 1536 * 2);
  bf16* kvb_wt = (bf16*)alloc((size_t)4096 * 512 * 2);
  bf16* o_wt   = (bf16*)alloc((size_t)2048 * 2048 * 2);
  float* rt    = (float*)alloc((size_t)2048 * 64 * 4);
  bf16* qac    = (bf16*)alloc((size_t)MR * 2304 * 2);  // fused q_a|ckv|pad
  bf16* q_a_n  = (bf16*)alloc((size_t)MR * 1536 * 2);
  bf16* kv_c_n = (bf16*)alloc((size_t)MR * 512 * 2);
  bf16* kr     = (bf16*)alloc((size_t)MR * 64 * 2);
  bf16* qbuf   = (bf16*)alloc((size_t)MR * 3072 * 2);
  bf16* kvbuf  = (bf16*)alloc((size_t)MR * 4096 * 2);
  bf16* attn_o = (bf16*)alloc((size_t)MR * 2048 * 2);

  k_prep<<<PREP_BLOCKS, 256, 0, stream>>>(x, q_a_w, kv_a_w, q_b_w, kv_b_w,
                                          o_w, x_bf, ab_wt, qb_wt, kvb_wt,
                                          o_wt, rt);
  // fused q_a + kv_a down-projection: 128x128 tiles, 2 blocks/CU (576 blocks)
  k_gemm2s<false><<<dim3(18, 32), 512, 0, stream>>>(x_bf, ab_wt, qac, 2304,
                                                    2048);
  k_norms<<<MR, 64, 0, stream>>>(qac, q_a_ln, kv_a_ln, rt, q_a_n, kv_c_n, kr);
  k_gemm8_dual<<<dim3(448), 512, 0, stream>>>(q_a_n, qb_wt, qbuf, kv_c_n,
                                              kvb_wt, kvbuf);
  k_attn<<<dim3(256), 512, 0, stream>>>(qbuf, kvbuf, kr, rt, attn_o);
  // o-projection: BN=128 variant -> 256 blocks (full CU coverage)
  k_gemm4n<true><<<dim3(16, 16), 512, 0, stream>>>(attn_o, o_wt, d_out, 2048,
                                                   2048);
}